// Round 6
// baseline (384.715 us; speedup 1.0000x reference)
//
#include <hip/hip_runtime.h>

typedef unsigned short ushort_t;
typedef unsigned int uint_t;
typedef __attribute__((ext_vector_type(8))) short bf16x8;
typedef __attribute__((ext_vector_type(4))) float f32x4;

#define N_NODES 50000
#define N_EDGES 1600000
#define NB_BKT 391    // dst buckets of 128 nodes
#define CAP_BKT 4608  // slack capacity per bucket (mean 4096, +8 sigma)
#define CAP_B 6144    // LDS staging entries per bucket in sortb phase
#define GBK 391       // bucket-append blocks (4096 edges each, 16/thread)
#define WPAD 72       // LDS row stride (ushorts): uniform bank spread for b128 reads
#define APAD 64       // atomic-target padding (ints/floats): one per 256B channel line
// D = 64, IN = 128, ED = 3, H = 1, STEPS = 3. Inputs f32; edge_index int32/int64.

__device__ __forceinline__ float bfu(ushort_t u) {
    return __uint_as_float(((uint_t)u) << 16);
}
__device__ __forceinline__ ushort_t f2b(float f) {
    uint_t x = __float_as_uint(f);
    uint_t r = (x + 0x7FFFu + ((x >> 16) & 1u)) >> 16;
    return (ushort_t)r;
}
__device__ __forceinline__ float sigm(float x) {
    return 1.0f / (1.0f + __expf(-x));
}
__device__ __forceinline__ float tanh_f(float x) {
    return 1.0f - 2.0f / (__expf(2.0f * x) + 1.0f);
}
__device__ __forceinline__ bf16x8 pack8(const float* v) {
    bf16x8 r;
#pragma unroll
    for (int j = 0; j < 8; ++j) r[j] = (short)f2b(v[j]);
    return r;
}
__device__ __forceinline__ int ld_src(const int* __restrict__ ei, int i, int f64) {
    return f64 ? ei[2 * i] : ei[i];
}
__device__ __forceinline__ int ld_dst(const int* __restrict__ ei, int i, int f64) {
    return f64 ? ei[2 * N_EDGES + 2 * i] : ei[N_EDGES + i];
}
__device__ __forceinline__ bool is_f64(const int* flag) { return flag[0] > 2048; }

// -------- ws-too-small sentinel
__global__ void k_sentinel(float* __restrict__ out, int n) {
    int i = blockIdx.x * 256 + threadIdx.x;
    if (i < n) out[i] = 100.0f;
}

// -------- merged prep: weights bf16 repack (blk<176), edge-dtype probe (blk==176),
//          gtail init (blk>=177; gtail padded to 256B stride per bucket)
__global__ void k_prep(const float* __restrict__ w_ih, const float* __restrict__ w_hh,
                       const float* __restrict__ conv_w, const float* __restrict__ mlp_w,
                       const float* __restrict__ lin_w, const int* __restrict__ ei,
                       ushort_t* __restrict__ wb, ushort_t* __restrict__ cwb,
                       ushort_t* __restrict__ mlpT, ushort_t* __restrict__ linT,
                       int* __restrict__ flag, int* __restrict__ gtail) {
    int blk = blockIdx.x;
    if (blk < 176) {
        int t = blk * 256 + threadIdx.x;
        if (t < 24576) {
            const float* w = (t < 12288) ? w_ih : w_hh;
            wb[t] = f2b(w[t < 12288 ? t : t - 12288]);
        } else if (t < 28672) {
            int r = t - 24576;
            int j = r >> 6, k = r & 63;
            cwb[j * 64 + k] = f2b(conv_w[k * 64 + j]);
        } else if (t < 36864) {
            int r = t - 28672;
            int j = r >> 7, k = r & 127;
            mlpT[j * 128 + k] = f2b(mlp_w[k * 64 + j]);
        } else if (t < 45056) {
            int r = t - 36864;
            int j = r >> 7, k = r & 127;
            linT[j * 128 + k] = f2b(lin_w[k * 64 + j]);
        }
    } else if (blk == 176) {
        __shared__ int red[256];
        int tid = threadIdx.x;
        int zeros = 0;
#pragma unroll
        for (int j = 0; j < 16; ++j) {
            int slot = (tid * 16 + j) * 2 + 1;  // odd int32 slots, in-bounds either way
            if (ei[slot] == 0) zeros++;
        }
        red[tid] = zeros;
        __syncthreads();
        for (int off = 128; off; off >>= 1) {
            if (tid < off) red[tid] += red[tid + off];
            __syncthreads();
        }
        if (tid == 0) flag[0] = red[0];  // direct store, no pre-zero needed
    } else {
        int b = (blk - 177) * 256 + threadIdx.x;
        if (b < NB_BKT) gtail[b * APAD] = b * CAP_BKT;
    }
}

// -------- merged: bucket-append (blocks [0,GBK)) || emb MFMA (blocks [GBK, GBK+gT))
// 16 edges/thread: doubles per-thread memory-level parallelism (latency-bound
// kernel: VALU 5%, HBM 21%, occ 28%) and halves per-block overheads.
__global__ __launch_bounds__(256) void k_embbkt(
    const int* __restrict__ ei, const int* __restrict__ flag,
    const float* __restrict__ ea, const float* __restrict__ ae,
    int* __restrict__ gtail, uint2* __restrict__ bkt, int e,
    const float* __restrict__ x, const ushort_t* __restrict__ mlpT,
    const float* __restrict__ mlp_b, float* __restrict__ h0, int n) {
    if (blockIdx.x < GBK) {
        // ---- bucket append: entry p.x = src | (dst&127)<<16 ; p.y = sel f32 bits
        __shared__ int cnt[NB_BKT];
        __shared__ int gbase[NB_BKT];
        for (int i = threadIdx.x; i < NB_BKT; i += 256) cnt[i] = 0;
        __syncthreads();
        int base = blockIdx.x * 4096;
        int f64 = is_f64(flag);
        float a0 = ae[0], a1 = ae[1], a2 = ae[2];
        uint_t w0[16], w1[16];
        int bk[16], rk[16];
#pragma unroll
        for (int j = 0; j < 16; ++j) {
            int i = base + j * 256 + threadIdx.x;
            bk[j] = -1;
            if (i < e) {
                int d = ld_dst(ei, i, f64);
                if ((uint_t)d < (uint_t)N_NODES) {
                    int s = ld_src(ei, i, f64);
                    if ((uint_t)s >= (uint_t)N_NODES) s = 0;
                    float ed = ea[i * 3] * a0 + ea[i * 3 + 1] * a1 + ea[i * 3 + 2] * a2;
                    bk[j] = d >> 7;
                    w0[j] = (uint_t)s | ((uint_t)(d & 127) << 16);
                    w1[j] = __float_as_uint(ed);
                    rk[j] = atomicAdd(&cnt[bk[j]], 1);
                }
            }
        }
        __syncthreads();
        for (int t = threadIdx.x; t < NB_BKT; t += 256) {
            int c = cnt[t];
            gbase[t] = c ? atomicAdd(&gtail[t * APAD], c) : 0;
        }
        __syncthreads();
#pragma unroll
        for (int j = 0; j < 16; ++j) {
            if (bk[j] >= 0) {
                int pos = gbase[bk[j]] + rk[j];
                if (pos < (bk[j] + 1) * CAP_BKT) {  // drop on impossible overflow
                    uint2 p;
                    p.x = w0[j];
                    p.y = w1[j];
                    bkt[pos] = p;
                }
            }
        }
    } else {
        // ---- h0 = x @ mlp_w + mlp_b via MFMA, 16 nodes/wave (K=128)
        int lane = threadIdx.x & 63;
        int wv = threadIdx.x >> 6;
        int tile = (blockIdx.x - GBK) * 4 + wv;
        if (tile * 16 >= n) return;
        int nb16 = tile * 16;
        int mrow = lane & 15, q = lane >> 4;
        const float* xp = x + (nb16 + mrow) * 128 + q * 8;
        bf16x8 a[4];
#pragma unroll
        for (int kc = 0; kc < 4; ++kc) {
            float hv[8];
            const float* p = xp + kc * 32;
#pragma unroll
            for (int j = 0; j < 8; ++j) hv[j] = p[j];
            a[kc] = pack8(hv);
        }
        f32x4 acc[4];
#pragma unroll
        for (int t = 0; t < 4; ++t) acc[t] = (f32x4){0.f, 0.f, 0.f, 0.f};
#pragma unroll
        for (int kc = 0; kc < 4; ++kc) {
#pragma unroll
            for (int t = 0; t < 4; ++t) {
                bf16x8 b =
                    *(const bf16x8*)(mlpT + (t * 16 + mrow) * 128 + kc * 32 + q * 8);
                acc[t] = __builtin_amdgcn_mfma_f32_16x16x32_bf16(a[kc], b, acc[t], 0, 0, 0);
            }
        }
#pragma unroll
        for (int t = 0; t < 4; ++t) {
            int j = t * 16 + mrow;
            float bias = mlp_b[j];
#pragma unroll
            for (int r = 0; r < 4; ++r)
                h0[(nb16 + q * 4 + r) * 64 + j] = acc[t][r] + bias;
        }
    }
}

// -------- merged: sortb (blocks [0,NB_BKT)) || BN stats (blocks [NB_BKT, NB_BKT+256))
__global__ __launch_bounds__(256) void k_statsort(
    const int* __restrict__ gtail, const uint2* __restrict__ bkt,
    uint_t* __restrict__ pk, int* __restrict__ rs, int n,
    const float* __restrict__ h0, float* __restrict__ stats) {
    __shared__ char smem[26624];
    int tid = threadIdx.x;
    if (blockIdx.x < NB_BKT) {
        int* red = (int*)smem;                 // 256 ints
        int* cnt = (int*)(smem + 1024);        // 128 ints
        int* sc = (int*)(smem + 1536);         // 128 ints
        uint_t* stg = (uint_t*)(smem + 2048);  // CAP_B uints (24 KiB)
        int b = blockIdx.x;
        int partial = 0;
        for (int i = tid; i < b; i += 256)
            partial += min(gtail[i * APAD] - i * CAP_BKT, CAP_BKT);
        red[tid] = partial;
        __syncthreads();
        for (int off = 128; off; off >>= 1) {
            if (tid < off) red[tid] += red[tid + off];
            __syncthreads();
        }
        int obase = red[0];
        int node0 = b * 128;
        int nloc = min(128, n - node0);
        int size = min(gtail[b * APAD] - b * CAP_BKT, CAP_BKT);
        const uint2* bin = bkt + b * CAP_BKT;
        for (int i = tid; i < 128; i += 256) cnt[i] = 0;
        __syncthreads();
        for (int ofs = tid; ofs < size; ofs += 256) {
            int dlow = (bin[ofs].x >> 16) & 127;
            atomicAdd(&cnt[dlow], 1);
        }
        __syncthreads();
        if (tid < 128) sc[tid] = cnt[tid];
        __syncthreads();
        for (int off = 1; off < 128; off <<= 1) {
            int add = (tid < 128 && tid >= off) ? sc[tid - off] : 0;
            __syncthreads();
            if (tid < 128) sc[tid] += add;
            __syncthreads();
        }
        if (tid < 128) sc[tid] -= cnt[tid];  // exclusive
        __syncthreads();
        if (tid < nloc) rs[node0 + tid] = obase + sc[tid];
        if (b == NB_BKT - 1 && tid == 0) rs[n] = obase + size;
        for (int i = tid; i < 128; i += 256) cnt[i] = 0;
        __syncthreads();
        for (int ofs = tid; ofs < size; ofs += 256) {
            uint2 p = bin[ofs];
            int dlow = (p.x >> 16) & 127;
            int r = atomicAdd(&cnt[dlow], 1);
            int pos = sc[dlow] + r;
            uint_t q = (p.x & 0xFFFFu) | ((uint_t)f2b(__uint_as_float(p.y)) << 16);
            if (pos < CAP_B) stg[pos] = q;
            else pk[obase + pos] = q;  // statistically impossible overflow fallback
        }
        __syncthreads();
        int wlim = min(size, CAP_B);
        for (int ofs = tid; ofs < wlim; ofs += 256) pk[obase + ofs] = stg[ofs];
    } else {
        float* ssum = (float*)smem;          // 256 floats
        float* ssq = (float*)(smem + 1024);  // 256 floats
        int gid = (blockIdx.x - NB_BKT) * 256 + tid;
        int col = gid & 63;
        int rg = gid >> 6;
        float s = 0.f, s2 = 0.f;
        for (int row = rg; row < n; row += 1024) {
            float v = h0[row * 64 + col];
            s += v;
            s2 += v * v;
        }
        ssum[tid] = s;
        ssq[tid] = s2;
        __syncthreads();
        if (tid < 64) {
            s = ssum[tid] + ssum[tid + 64] + ssum[tid + 128] + ssum[tid + 192];
            s2 = ssq[tid] + ssq[tid + 64] + ssq[tid + 128] + ssq[tid + 192];
            atomicAdd(&stats[tid * APAD], s);
            atomicAdd(&stats[(64 + tid) * APAD], s2);
        }
    }
}

// -------- step-0 xt = h @ conv_w via MFMA, with fused BN+ReLU (normalizes h in place)
__global__ __launch_bounds__(256) void k_xt(float* __restrict__ h,
                                            const ushort_t* __restrict__ cwb,
                                            const float* __restrict__ att_dst,
                                            const float* __restrict__ att_src,
                                            const float* __restrict__ bn_g,
                                            const float* __restrict__ bn_b,
                                            const float* __restrict__ stats,
                                            float inv_n,
                                            ushort_t* __restrict__ xt,
                                            float* __restrict__ adst,
                                            float* __restrict__ asrc, int n) {
    __shared__ float scb[64], shb[64];
    {
        int tid = threadIdx.x;
        if (tid < 64) {
            float mu = stats[tid * APAD] * inv_n;
            float var = fmaxf(stats[(64 + tid) * APAD] * inv_n - mu * mu, 0.f);
            float sc = rsqrtf(var + 1e-5f) * bn_g[tid];
            scb[tid] = sc;
            shb[tid] = bn_b[tid] - mu * sc;
        }
        __syncthreads();
    }
    int lane = threadIdx.x & 63;
    int wv = threadIdx.x >> 6;
    int tile = blockIdx.x * 4 + wv;
    if (tile * 16 >= n) return;
    int nb16 = tile * 16;
    int mrow = lane & 15, q = lane >> 4;
    bf16x8 ah[2];
    {
        float* hp = h + (nb16 + mrow) * 64 + q * 8;
        float hv[8];
#pragma unroll
        for (int kh = 0; kh < 2; ++kh) {
            float* p = hp + kh * 32;
            int cb = kh * 32 + q * 8;
#pragma unroll
            for (int j = 0; j < 8; ++j) {
                hv[j] = fmaxf(p[j] * scb[cb + j] + shb[cb + j], 0.f);
                p[j] = hv[j];  // write normalized h back for k_gruxt
            }
            ah[kh] = pack8(hv);
        }
    }
    f32x4 acc[4];
#pragma unroll
    for (int t = 0; t < 4; ++t) acc[t] = (f32x4){0.f, 0.f, 0.f, 0.f};
#pragma unroll
    for (int kh = 0; kh < 2; ++kh) {
#pragma unroll
        for (int t = 0; t < 4; ++t) {
            bf16x8 b = *(const bf16x8*)(cwb + (t * 16 + mrow) * 64 + kh * 32 + q * 8);
            acc[t] = __builtin_amdgcn_mfma_f32_16x16x32_bf16(ah[kh], b, acc[t], 0, 0, 0);
        }
    }
    float sd[4] = {0, 0, 0, 0}, ss[4] = {0, 0, 0, 0};
#pragma unroll
    for (int t = 0; t < 4; ++t) {
        int j = t * 16 + mrow;
        float ad = att_dst[j], as = att_src[j];
#pragma unroll
        for (int r = 0; r < 4; ++r) {
            float v = acc[t][r];
            xt[(nb16 + q * 4 + r) * 64 + j] = f2b(v);
            sd[r] += v * ad;
            ss[r] += v * as;
        }
    }
#pragma unroll
    for (int off = 1; off < 16; off <<= 1) {
#pragma unroll
        for (int r = 0; r < 4; ++r) {
            sd[r] += __shfl_xor(sd[r], off);
            ss[r] += __shfl_xor(ss[r], off);
        }
    }
    if (mrow == 0) {
#pragma unroll
        for (int r = 0; r < 4; ++r) {
            adst[nb16 + q * 4 + r] = sd[r];
            asrc[nb16 + q * 4 + r] = ss[r];
        }
    }
}

// -------- single-pass segment softmax + aggregation; 4B pk entries; bf16 m out.
// asrc computed IN-REGISTER from the gathered xt row (dot with att_src, 8 FMA +
// 3 intra-group shfl_xor) instead of a per-edge random 4B gather: removes 1.6M
// dependent L2-line pulls per launch. dsum accumulated per-g-lane, reduced over
// lanes 8/16/32 (within-cb duplicates are equal by construction).
__global__ __launch_bounds__(256) void k_agg(const int* __restrict__ rs,
                                             const uint_t* __restrict__ pk,
                                             const float* __restrict__ adst,
                                             const float* __restrict__ att_src,
                                             const ushort_t* __restrict__ xt,
                                             ushort_t* __restrict__ m, int n) {
    __shared__ float s_w[4][64];
    __shared__ int s_s[4][64];
    int lane = threadIdx.x & 63;
    int wv = threadIdx.x >> 6;
    int v = blockIdx.x * 4 + wv;
    if (v >= n) return;
    int start = rs[v], end = rs[v + 1];
    if (start >= end) {
        m[v * 64 + lane] = 0;
        return;
    }
    float adv = adst[v];
    int g = lane >> 3;        // edge sub-slot 0..7
    int cb = (lane & 7) * 8;  // channel base
    float asv[8];
#pragma unroll
    for (int j = 0; j < 8; ++j) asv[j] = att_src[cb + j];
    float acc[8] = {0, 0, 0, 0, 0, 0, 0, 0};
    float dsum = 0.f;
    for (int base = start; base < end; base += 64) {
        int e = base + lane;
        float et = 0.f;
        int s = 0;
        if (e < end) {
            uint_t p = pk[e];
            s = (int)(p & 0xFFFFu);
            et = bfu((ushort_t)(p >> 16));
        }
        s_w[wv][lane] = et;
        s_s[wv][lane] = s;
        int cnt = min(64, end - base);
        int nb8 = (cnt + 7) >> 3;
        for (int tb = 0; tb < nb8; ++tb) {
            int sl = tb * 8 + g;
            float et8 = s_w[wv][sl];
            int s8 = s_s[wv][sl];
            uint4 qv = *(const uint4*)(xt + s8 * 64 + cb);
            float f0 = __uint_as_float(qv.x << 16);
            float f1 = __uint_as_float(qv.x & 0xFFFF0000u);
            float f2 = __uint_as_float(qv.y << 16);
            float f3 = __uint_as_float(qv.y & 0xFFFF0000u);
            float f4 = __uint_as_float(qv.z << 16);
            float f5 = __uint_as_float(qv.z & 0xFFFF0000u);
            float f6 = __uint_as_float(qv.w << 16);
            float f7 = __uint_as_float(qv.w & 0xFFFF0000u);
            float part = f0 * asv[0] + f1 * asv[1] + f2 * asv[2] + f3 * asv[3] +
                         f4 * asv[4] + f5 * asv[5] + f6 * asv[6] + f7 * asv[7];
            part += __shfl_xor(part, 1);
            part += __shfl_xor(part, 2);
            part += __shfl_xor(part, 4);
            float l = adv + part + et8;
            l = (l >= 0.f) ? l : 0.2f * l;
            float w8 = (sl < cnt) ? __expf(l) : 0.f;
            dsum += w8;
            acc[0] += w8 * f0;
            acc[1] += w8 * f1;
            acc[2] += w8 * f2;
            acc[3] += w8 * f3;
            acc[4] += w8 * f4;
            acc[5] += w8 * f5;
            acc[6] += w8 * f6;
            acc[7] += w8 * f7;
        }
    }
    dsum += __shfl_xor(dsum, 8);
    dsum += __shfl_xor(dsum, 16);
    dsum += __shfl_xor(dsum, 32);
#pragma unroll
    for (int off = 8; off < 64; off <<= 1) {
#pragma unroll
        for (int j = 0; j < 8; ++j) acc[j] += __shfl_xor(acc[j], off);
    }
    float inv = 1.0f / fmaxf(dsum, 1e-20f);
    if (g == 0) {
        uint4 o;
        o.x = (uint_t)f2b(fmaxf(acc[0] * inv, 0.f)) |
              ((uint_t)f2b(fmaxf(acc[1] * inv, 0.f)) << 16);
        o.y = (uint_t)f2b(fmaxf(acc[2] * inv, 0.f)) |
              ((uint_t)f2b(fmaxf(acc[3] * inv, 0.f)) << 16);
        o.z = (uint_t)f2b(fmaxf(acc[4] * inv, 0.f)) |
              ((uint_t)f2b(fmaxf(acc[5] * inv, 0.f)) << 16);
        o.w = (uint_t)f2b(fmaxf(acc[6] * inv, 0.f)) |
              ((uint_t)f2b(fmaxf(acc[7] * inv, 0.f)) << 16);
        *(uint4*)(m + v * 64 + cb) = o;
    }
}

// -------- fused GRU + next-step xt: weights in padded LDS, 16 nodes/wave
__global__ __launch_bounds__(256) void k_gruxt(
    const ushort_t* __restrict__ mb, float* __restrict__ h,
    const ushort_t* __restrict__ wb, const ushort_t* __restrict__ cwb,
    const float* __restrict__ b_ih, const float* __restrict__ b_hh,
    const float* __restrict__ att_dst, const float* __restrict__ att_src,
    int do_xt, ushort_t* __restrict__ xt, float* __restrict__ adst,
    float* __restrict__ asrc, int n) {
    __shared__ ushort_t swb[384 * WPAD];  // 55,296 B
    __shared__ ushort_t scw[64 * WPAD];   // 9,216 B -> 64,512 B total
    {
        const uint2* src = (const uint2*)wb;  // 4 ushorts per uint2
        for (int g = threadIdx.x; g < 6144; g += 256) {
            uint2 v = src[g];
            int row = g >> 4;
            int col = (g & 15) * 4;
            *(uint2*)(swb + row * WPAD + col) = v;
        }
        const uint2* srcc = (const uint2*)cwb;
        for (int g = threadIdx.x; g < 1024; g += 256) {
            uint2 v = srcc[g];
            int row = g >> 4;
            int col = (g & 15) * 4;
            *(uint2*)(scw + row * WPAD + col) = v;
        }
    }
    __syncthreads();
    int lane = threadIdx.x & 63;
    int wv = threadIdx.x >> 6;
    int tile = blockIdx.x * 4 + wv;
    if (tile * 16 >= n) return;
    int nb16 = tile * 16;
    int mrow = lane & 15, q = lane >> 4;
    // prefetch epilogue h (C-layout positions) early — latency hidden by MFMAs
    float hp[4][4];
#pragma unroll
    for (int t = 0; t < 4; ++t)
#pragma unroll
        for (int r = 0; r < 4; ++r)
            hp[t][r] = h[(nb16 + q * 4 + r) * 64 + t * 16 + mrow];
    bf16x8 am[2], ah[2];
    {
        const ushort_t* mp = mb + (nb16 + mrow) * 64 + q * 8;
        am[0] = *(const bf16x8*)(mp);
        am[1] = *(const bf16x8*)(mp + 32);
        const float* hpt = h + (nb16 + mrow) * 64 + q * 8;
        float hv[8];
#pragma unroll
        for (int j = 0; j < 8; ++j) hv[j] = hpt[j];
        ah[0] = pack8(hv);
#pragma unroll
        for (int j = 0; j < 8; ++j) hv[j] = hpt[32 + j];
        ah[1] = pack8(hv);
    }
    f32x4 acc[24];
#pragma unroll
    for (int t = 0; t < 24; ++t) acc[t] = (f32x4){0.f, 0.f, 0.f, 0.f};
#pragma unroll
    for (int kh = 0; kh < 2; ++kh) {
#pragma unroll
        for (int t = 0; t < 12; ++t) {
            bf16x8 b = *(const bf16x8*)(swb + (t * 16 + mrow) * WPAD + kh * 32 + q * 8);
            acc[t] = __builtin_amdgcn_mfma_f32_16x16x32_bf16(am[kh], b, acc[t], 0, 0, 0);
        }
#pragma unroll
        for (int t = 0; t < 12; ++t) {
            bf16x8 b =
                *(const bf16x8*)(swb + (192 + t * 16 + mrow) * WPAD + kh * 32 + q * 8);
            acc[12 + t] =
                __builtin_amdgcn_mfma_f32_16x16x32_bf16(ah[kh], b, acc[12 + t], 0, 0, 0);
        }
    }
#pragma unroll
    for (int t = 0; t < 4; ++t) {
        int j = t * 16 + mrow;
        float bir = b_ih[j], biz = b_ih[64 + j], bin = b_ih[128 + j];
        float bhr = b_hh[j], bhz = b_hh[64 + j], bhn = b_hh[128 + j];
#pragma unroll
        for (int r = 0; r < 4; ++r) {
            int node = nb16 + q * 4 + r;
            float gr = acc[t][r] + bir + acc[12 + t][r] + bhr;
            float gz = acc[4 + t][r] + biz + acc[16 + t][r] + bhz;
            float rr = sigm(gr);
            float zz = sigm(gz);
            float tt = acc[8 + t][r] + bin + rr * (acc[20 + t][r] + bhn);
            h[node * 64 + j] = (1.f - zz) * tanh_f(tt) + zz * hp[t][r];
        }
    }
    if (!do_xt) return;
    __threadfence_block();  // drain wave's h stores (lockstep => all 64 lanes ordered)
    // reload new h in A-layout (same 16 nodes, just written — L1/L2 hit)
    bf16x8 ah2[2];
    {
        const float* hpt = h + (nb16 + mrow) * 64 + q * 8;
        float hv[8];
#pragma unroll
        for (int j = 0; j < 8; ++j) hv[j] = hpt[j];
        ah2[0] = pack8(hv);
#pragma unroll
        for (int j = 0; j < 8; ++j) hv[j] = hpt[32 + j];
        ah2[1] = pack8(hv);
    }
    f32x4 xacc[4];
#pragma unroll
    for (int t = 0; t < 4; ++t) xacc[t] = (f32x4){0.f, 0.f, 0.f, 0.f};
#pragma unroll
    for (int kh = 0; kh < 2; ++kh) {
#pragma unroll
        for (int t = 0; t < 4; ++t) {
            bf16x8 b = *(const bf16x8*)(scw + (t * 16 + mrow) * WPAD + kh * 32 + q * 8);
            xacc[t] = __builtin_amdgcn_mfma_f32_16x16x32_bf16(ah2[kh], b, xacc[t], 0, 0, 0);
        }
    }
    float sd[4] = {0, 0, 0, 0}, ss[4] = {0, 0, 0, 0};
#pragma unroll
    for (int t = 0; t < 4; ++t) {
        int j = t * 16 + mrow;
        float ad = att_dst[j], as = att_src[j];
#pragma unroll
        for (int r = 0; r < 4; ++r) {
            float v = xacc[t][r];
            xt[(nb16 + q * 4 + r) * 64 + j] = f2b(v);
            sd[r] += v * ad;
            ss[r] += v * as;
        }
    }
#pragma unroll
    for (int off = 1; off < 16; off <<= 1) {
#pragma unroll
        for (int r = 0; r < 4; ++r) {
            sd[r] += __shfl_xor(sd[r], off);
            ss[r] += __shfl_xor(ss[r], off);
        }
    }
    if (mrow == 0) {
#pragma unroll
        for (int r = 0; r < 4; ++r) {
            adst[nb16 + q * 4 + r] = sd[r];
            asrc[nb16 + q * 4 + r] = ss[r];
        }
    }
}

// -------- out = x @ lin_w + lin_b + h via MFMA (K=128, f32 x in-reg cast)
__global__ __launch_bounds__(256) void k_out(const float* __restrict__ x,
                                             const ushort_t* __restrict__ linT,
                                             const float* __restrict__ lin_b,
                                             const float* __restrict__ h,
                                             float* __restrict__ out, int n) {
    int lane = threadIdx.x & 63;
    int wv = threadIdx.x >> 6;
    int tile = blockIdx.x * 4 + wv;
    if (tile * 16 >= n) return;
    int nb16 = tile * 16;
    int mrow = lane & 15, q = lane >> 4;
    const float* xp = x + (nb16 + mrow) * 128 + q * 8;
    bf16x8 a[4];
#pragma unroll
    for (int kc = 0; kc < 4; ++kc) {
        float hv[8];
        const float* p = xp + kc * 32;
#pragma unroll
        for (int j = 0; j < 8; ++j) hv[j] = p[j];
        a[kc] = pack8(hv);
    }
    f32x4 acc[4];
#pragma unroll
    for (int t = 0; t < 4; ++t) acc[t] = (f32x4){0.f, 0.f, 0.f, 0.f};
#pragma unroll
    for (int kc = 0; kc < 4; ++kc) {
#pragma unroll
        for (int t = 0; t < 4; ++t) {
            bf16x8 b = *(const bf16x8*)(linT + (t * 16 + mrow) * 128 + kc * 32 + q * 8);
            acc[t] = __builtin_amdgcn_mfma_f32_16x16x32_bf16(a[kc], b, acc[t], 0, 0, 0);
        }
    }
#pragma unroll
    for (int t = 0; t < 4; ++t) {
        int j = t * 16 + mrow;
        float bias = lin_b[j];
#pragma unroll
        for (int r = 0; r < 4; ++r) {
            int node = nb16 + q * 4 + r;
            out[node * 64 + j] = acc[t][r] + bias + h[node * 64 + j];
        }
    }
}

extern "C" void kernel_launch(void* const* d_in, const int* in_sizes, int n_in,
                              void* d_out, int out_size, void* d_ws, size_t ws_size,
                              hipStream_t stream) {
    const float* x = (const float*)d_in[0];
    const float* edge_attr = (const float*)d_in[1];
    const float* mlp_w = (const float*)d_in[2];
    const float* mlp_b = (const float*)d_in[3];
    const float* bn_g = (const float*)d_in[4];
    const float* bn_b = (const float*)d_in[5];
    const float* conv_w = (const float*)d_in[6];
    const float* att_dst = (const float*)d_in[7];
    const float* att_src = (const float*)d_in[8];
    const float* att_edge = (const float*)d_in[9];
    const float* w_ih = (const float*)d_in[10];
    const float* w_hh = (const float*)d_in[11];
    const float* b_ih = (const float*)d_in[12];
    const float* b_hh = (const float*)d_in[13];
    const float* lin_w = (const float*)d_in[14];
    const float* lin_b = (const float*)d_in[15];
    const int* ei = (const int*)d_in[16];

    char* ws = (char*)d_ws;
    float* f_h = (float*)(ws + 0);                // 12,800,000
    ushort_t* mb = (ushort_t*)(ws + 12800000);    // 6,400,000
    ushort_t* xt = (ushort_t*)(ws + 19200000);    // 6,400,000
    uint2* bkt = (uint2*)(ws + 25600000);         // 14,413,824 slack buckets
    uint_t* pk = (uint_t*)(ws + 40013824);        // 6,400,000 dense 4B entries
    float* f_adst = (float*)(ws + 46413824);      // 200,192
    float* f_asrc = (float*)(ws + 46614016);      // 200,192
    int* row_start = (int*)(ws + 46814208);       // 200,448 (n+1)
    float* stats = (float*)(ws + 47014656);       // 32,768 (128 slots, 256B stride)
    int* flag = (int*)(ws + 47047424);            // 512
    ushort_t* wb = (ushort_t*)(ws + 47047936);    // 49,152
    ushort_t* cwb = (ushort_t*)(ws + 47097088);   // 8,192
    ushort_t* mlpT = (ushort_t*)(ws + 47105280);  // 16,384
    ushort_t* linT = (ushort_t*)(ws + 47121664);  // 16,384
    int* gtail = (int*)(ws + 47138048);           // 100,096 (391 slots, 256B stride)

    const size_t needed = 47238144;
    if (ws_size < needed) {
        k_sentinel<<<(out_size + 255) / 256, 256, 0, stream>>>((float*)d_out, out_size);
        return;
    }

    const int n = N_NODES, e = N_EDGES;
    const int gT = ((n + 15) / 16 + 3) / 4;  // 782 (16-node MFMA tiles)
    const int gN4 = (n + 3) / 4;             // 12500
    const int gPrep = 176 + 1 + (NB_BKT + 255) / 256;  // 179
    const float inv_n = 1.0f / (float)n;

    hipMemsetAsync(stats, 0, 32768, stream);

    k_prep<<<gPrep, 256, 0, stream>>>(w_ih, w_hh, conv_w, mlp_w, lin_w, ei, wb, cwb,
                                      mlpT, linT, flag, gtail);
    // bucket-append (391 blocks, 16 edges/thread) || emb MFMA (782 blocks)
    k_embbkt<<<GBK + gT, 256, 0, stream>>>(ei, flag, edge_attr, att_edge, gtail, bkt, e,
                                           x, mlpT, mlp_b, f_h, n);
    // sortb (391 blocks) || BN stats (256 blocks) in one dispatch
    k_statsort<<<NB_BKT + 256, 256, 0, stream>>>(gtail, bkt, pk, row_start, n, f_h,
                                                 stats);
    // step-0 xt with fused BN+ReLU
    k_xt<<<gT, 256, 0, stream>>>(f_h, cwb, att_dst, att_src, bn_g, bn_b, stats, inv_n,
                                 xt, f_adst, f_asrc, n);

    for (int s = 0; s < 3; ++s) {
        k_agg<<<gN4, 256, 0, stream>>>(row_start, pk, f_adst, att_src, xt, mb, n);
        k_gruxt<<<gT, 256, 0, stream>>>(mb, f_h, wb, cwb, b_ih, b_hh, att_dst, att_src,
                                        (s < 2) ? 1 : 0, xt, f_adst, f_asrc, n);
    }

    k_out<<<gT, 256, 0, stream>>>(x, linT, lin_b, f_h, (float*)d_out, n);
}

// Round 7
// 383.256 us; speedup vs baseline: 1.0038x; 1.0038x over previous
//
#include <hip/hip_runtime.h>

typedef unsigned short ushort_t;
typedef unsigned int uint_t;
typedef __attribute__((ext_vector_type(8))) short bf16x8;
typedef __attribute__((ext_vector_type(4))) float f32x4;

#define N_NODES 50000
#define N_EDGES 1600000
#define NB_BKT 391    // dst buckets of 128 nodes
#define CAP_BKT 4608  // slack capacity per bucket (mean 4096, +8 sigma)
#define CAP_B 6144    // LDS staging entries per bucket in sortb phase
#define GBK 782       // bucket-append blocks (2048 edges each, 8/thread — proven)
#define WPAD 72       // LDS row stride (ushorts): uniform bank spread for b128 reads
#define APAD 64       // atomic-target padding (ints/floats): one per 256B channel line
// D = 64, IN = 128, ED = 3, H = 1, STEPS = 3. Inputs f32; edge_index int32/int64.

__device__ __forceinline__ float bfu(ushort_t u) {
    return __uint_as_float(((uint_t)u) << 16);
}
__device__ __forceinline__ ushort_t f2b(float f) {
    uint_t x = __float_as_uint(f);
    uint_t r = (x + 0x7FFFu + ((x >> 16) & 1u)) >> 16;
    return (ushort_t)r;
}
__device__ __forceinline__ float sigm(float x) {
    return 1.0f / (1.0f + __expf(-x));
}
__device__ __forceinline__ float tanh_f(float x) {
    return 1.0f - 2.0f / (__expf(2.0f * x) + 1.0f);
}
__device__ __forceinline__ bf16x8 pack8(const float* v) {
    bf16x8 r;
#pragma unroll
    for (int j = 0; j < 8; ++j) r[j] = (short)f2b(v[j]);
    return r;
}
__device__ __forceinline__ int ld_src(const int* __restrict__ ei, int i, int f64) {
    return f64 ? ei[2 * i] : ei[i];
}
__device__ __forceinline__ int ld_dst(const int* __restrict__ ei, int i, int f64) {
    return f64 ? ei[2 * N_EDGES + 2 * i] : ei[N_EDGES + i];
}
__device__ __forceinline__ bool is_f64(const int* flag) { return flag[0] > 2048; }

// -------- ws-too-small sentinel
__global__ void k_sentinel(float* __restrict__ out, int n) {
    int i = blockIdx.x * 256 + threadIdx.x;
    if (i < n) out[i] = 100.0f;
}

// -------- merged prep: weights bf16 repack (blk<176), edge-dtype probe (blk==176),
//          gtail init (blk>=177; gtail padded to 256B stride per bucket)
__global__ void k_prep(const float* __restrict__ w_ih, const float* __restrict__ w_hh,
                       const float* __restrict__ conv_w, const float* __restrict__ mlp_w,
                       const float* __restrict__ lin_w, const int* __restrict__ ei,
                       ushort_t* __restrict__ wb, ushort_t* __restrict__ cwb,
                       ushort_t* __restrict__ mlpT, ushort_t* __restrict__ linT,
                       int* __restrict__ flag, int* __restrict__ gtail) {
    int blk = blockIdx.x;
    if (blk < 176) {
        int t = blk * 256 + threadIdx.x;
        if (t < 24576) {
            const float* w = (t < 12288) ? w_ih : w_hh;
            wb[t] = f2b(w[t < 12288 ? t : t - 12288]);
        } else if (t < 28672) {
            int r = t - 24576;
            int j = r >> 6, k = r & 63;
            cwb[j * 64 + k] = f2b(conv_w[k * 64 + j]);
        } else if (t < 36864) {
            int r = t - 28672;
            int j = r >> 7, k = r & 127;
            mlpT[j * 128 + k] = f2b(mlp_w[k * 64 + j]);
        } else if (t < 45056) {
            int r = t - 36864;
            int j = r >> 7, k = r & 127;
            linT[j * 128 + k] = f2b(lin_w[k * 64 + j]);
        }
    } else if (blk == 176) {
        __shared__ int red[256];
        int tid = threadIdx.x;
        int zeros = 0;
#pragma unroll
        for (int j = 0; j < 16; ++j) {
            int slot = (tid * 16 + j) * 2 + 1;  // odd int32 slots, in-bounds either way
            if (ei[slot] == 0) zeros++;
        }
        red[tid] = zeros;
        __syncthreads();
        for (int off = 128; off; off >>= 1) {
            if (tid < off) red[tid] += red[tid + off];
            __syncthreads();
        }
        if (tid == 0) flag[0] = red[0];  // direct store, no pre-zero needed
    } else {
        int b = (blk - 177) * 256 + threadIdx.x;
        if (b < NB_BKT) gtail[b * APAD] = b * CAP_BKT;
    }
}

// -------- merged: bucket-append (blocks [0,GBK)) || emb MFMA (blocks [GBK, GBK+gT))
__global__ __launch_bounds__(256) void k_embbkt(
    const int* __restrict__ ei, const int* __restrict__ flag,
    const float* __restrict__ ea, const float* __restrict__ ae,
    int* __restrict__ gtail, uint2* __restrict__ bkt, int e,
    const float* __restrict__ x, const ushort_t* __restrict__ mlpT,
    const float* __restrict__ mlp_b, float* __restrict__ h0, int n) {
    if (blockIdx.x < GBK) {
        // ---- bucket append: entry p.x = src | (dst&127)<<16 ; p.y = sel f32 bits
        __shared__ int cnt[NB_BKT];
        __shared__ int gbase[NB_BKT];
        for (int i = threadIdx.x; i < NB_BKT; i += 256) cnt[i] = 0;
        __syncthreads();
        int base = blockIdx.x * 2048;
        int f64 = is_f64(flag);
        float a0 = ae[0], a1 = ae[1], a2 = ae[2];
        uint_t w0[8], w1[8];
        int bk[8], rk[8];
#pragma unroll
        for (int j = 0; j < 8; ++j) {
            int i = base + j * 256 + threadIdx.x;
            bk[j] = -1;
            if (i < e) {
                int d = ld_dst(ei, i, f64);
                if ((uint_t)d < (uint_t)N_NODES) {
                    int s = ld_src(ei, i, f64);
                    if ((uint_t)s >= (uint_t)N_NODES) s = 0;
                    float ed = ea[i * 3] * a0 + ea[i * 3 + 1] * a1 + ea[i * 3 + 2] * a2;
                    bk[j] = d >> 7;
                    w0[j] = (uint_t)s | ((uint_t)(d & 127) << 16);
                    w1[j] = __float_as_uint(ed);
                    rk[j] = atomicAdd(&cnt[bk[j]], 1);
                }
            }
        }
        __syncthreads();
        for (int t = threadIdx.x; t < NB_BKT; t += 256) {
            int c = cnt[t];
            gbase[t] = c ? atomicAdd(&gtail[t * APAD], c) : 0;
        }
        __syncthreads();
#pragma unroll
        for (int j = 0; j < 8; ++j) {
            if (bk[j] >= 0) {
                int pos = gbase[bk[j]] + rk[j];
                if (pos < (bk[j] + 1) * CAP_BKT) {  // drop on impossible overflow
                    uint2 p;
                    p.x = w0[j];
                    p.y = w1[j];
                    bkt[pos] = p;
                }
            }
        }
    } else {
        // ---- h0 = x @ mlp_w + mlp_b via MFMA, 16 nodes/wave (K=128)
        int lane = threadIdx.x & 63;
        int wv = threadIdx.x >> 6;
        int tile = (blockIdx.x - GBK) * 4 + wv;
        if (tile * 16 >= n) return;
        int nb16 = tile * 16;
        int mrow = lane & 15, q = lane >> 4;
        const float* xp = x + (nb16 + mrow) * 128 + q * 8;
        bf16x8 a[4];
#pragma unroll
        for (int kc = 0; kc < 4; ++kc) {
            float hv[8];
            const float* p = xp + kc * 32;
#pragma unroll
            for (int j = 0; j < 8; ++j) hv[j] = p[j];
            a[kc] = pack8(hv);
        }
        f32x4 acc[4];
#pragma unroll
        for (int t = 0; t < 4; ++t) acc[t] = (f32x4){0.f, 0.f, 0.f, 0.f};
#pragma unroll
        for (int kc = 0; kc < 4; ++kc) {
#pragma unroll
            for (int t = 0; t < 4; ++t) {
                bf16x8 b =
                    *(const bf16x8*)(mlpT + (t * 16 + mrow) * 128 + kc * 32 + q * 8);
                acc[t] = __builtin_amdgcn_mfma_f32_16x16x32_bf16(a[kc], b, acc[t], 0, 0, 0);
            }
        }
#pragma unroll
        for (int t = 0; t < 4; ++t) {
            int j = t * 16 + mrow;
            float bias = mlp_b[j];
#pragma unroll
            for (int r = 0; r < 4; ++r)
                h0[(nb16 + q * 4 + r) * 64 + j] = acc[t][r] + bias;
        }
    }
}

// -------- merged: sortb (blocks [0,NB_BKT)) || BN stats (blocks [NB_BKT, NB_BKT+256))
__global__ __launch_bounds__(256) void k_statsort(
    const int* __restrict__ gtail, const uint2* __restrict__ bkt,
    uint_t* __restrict__ pk, int* __restrict__ rs, int n,
    const float* __restrict__ h0, float* __restrict__ stats) {
    __shared__ char smem[26624];
    int tid = threadIdx.x;
    if (blockIdx.x < NB_BKT) {
        int* red = (int*)smem;                 // 256 ints
        int* cnt = (int*)(smem + 1024);        // 128 ints
        int* sc = (int*)(smem + 1536);         // 128 ints
        uint_t* stg = (uint_t*)(smem + 2048);  // CAP_B uints (24 KiB)
        int b = blockIdx.x;
        int partial = 0;
        for (int i = tid; i < b; i += 256)
            partial += min(gtail[i * APAD] - i * CAP_BKT, CAP_BKT);
        red[tid] = partial;
        __syncthreads();
        for (int off = 128; off; off >>= 1) {
            if (tid < off) red[tid] += red[tid + off];
            __syncthreads();
        }
        int obase = red[0];
        int node0 = b * 128;
        int nloc = min(128, n - node0);
        int size = min(gtail[b * APAD] - b * CAP_BKT, CAP_BKT);
        const uint2* bin = bkt + b * CAP_BKT;
        for (int i = tid; i < 128; i += 256) cnt[i] = 0;
        __syncthreads();
        for (int ofs = tid; ofs < size; ofs += 256) {
            int dlow = (bin[ofs].x >> 16) & 127;
            atomicAdd(&cnt[dlow], 1);
        }
        __syncthreads();
        if (tid < 128) sc[tid] = cnt[tid];
        __syncthreads();
        for (int off = 1; off < 128; off <<= 1) {
            int add = (tid < 128 && tid >= off) ? sc[tid - off] : 0;
            __syncthreads();
            if (tid < 128) sc[tid] += add;
            __syncthreads();
        }
        if (tid < 128) sc[tid] -= cnt[tid];  // exclusive
        __syncthreads();
        if (tid < nloc) rs[node0 + tid] = obase + sc[tid];
        if (b == NB_BKT - 1 && tid == 0) rs[n] = obase + size;
        for (int i = tid; i < 128; i += 256) cnt[i] = 0;
        __syncthreads();
        for (int ofs = tid; ofs < size; ofs += 256) {
            uint2 p = bin[ofs];
            int dlow = (p.x >> 16) & 127;
            int r = atomicAdd(&cnt[dlow], 1);
            int pos = sc[dlow] + r;
            uint_t q = (p.x & 0xFFFFu) | ((uint_t)f2b(__uint_as_float(p.y)) << 16);
            if (pos < CAP_B) stg[pos] = q;
            else pk[obase + pos] = q;  // statistically impossible overflow fallback
        }
        __syncthreads();
        int wlim = min(size, CAP_B);
        for (int ofs = tid; ofs < wlim; ofs += 256) pk[obase + ofs] = stg[ofs];
    } else {
        float* ssum = (float*)smem;          // 256 floats
        float* ssq = (float*)(smem + 1024);  // 256 floats
        int gid = (blockIdx.x - NB_BKT) * 256 + tid;
        int col = gid & 63;
        int rg = gid >> 6;
        float s = 0.f, s2 = 0.f;
        for (int row = rg; row < n; row += 1024) {
            float v = h0[row * 64 + col];
            s += v;
            s2 += v * v;
        }
        ssum[tid] = s;
        ssq[tid] = s2;
        __syncthreads();
        if (tid < 64) {
            s = ssum[tid] + ssum[tid + 64] + ssum[tid + 128] + ssum[tid + 192];
            s2 = ssq[tid] + ssq[tid + 64] + ssq[tid + 128] + ssq[tid + 192];
            atomicAdd(&stats[tid * APAD], s);
            atomicAdd(&stats[(64 + tid) * APAD], s2);
        }
    }
}

// -------- step-0 xt = h @ conv_w via MFMA, with fused BN+ReLU (normalizes h in place)
__global__ __launch_bounds__(256) void k_xt(float* __restrict__ h,
                                            const ushort_t* __restrict__ cwb,
                                            const float* __restrict__ att_dst,
                                            const float* __restrict__ att_src,
                                            const float* __restrict__ bn_g,
                                            const float* __restrict__ bn_b,
                                            const float* __restrict__ stats,
                                            float inv_n,
                                            ushort_t* __restrict__ xt,
                                            float* __restrict__ adst,
                                            float* __restrict__ asrc, int n) {
    __shared__ float scb[64], shb[64];
    {
        int tid = threadIdx.x;
        if (tid < 64) {
            float mu = stats[tid * APAD] * inv_n;
            float var = fmaxf(stats[(64 + tid) * APAD] * inv_n - mu * mu, 0.f);
            float sc = rsqrtf(var + 1e-5f) * bn_g[tid];
            scb[tid] = sc;
            shb[tid] = bn_b[tid] - mu * sc;
        }
        __syncthreads();
    }
    int lane = threadIdx.x & 63;
    int wv = threadIdx.x >> 6;
    int tile = blockIdx.x * 4 + wv;
    if (tile * 16 >= n) return;
    int nb16 = tile * 16;
    int mrow = lane & 15, q = lane >> 4;
    bf16x8 ah[2];
    {
        float* hp = h + (nb16 + mrow) * 64 + q * 8;
        float hv[8];
#pragma unroll
        for (int kh = 0; kh < 2; ++kh) {
            float* p = hp + kh * 32;
            int cb = kh * 32 + q * 8;
#pragma unroll
            for (int j = 0; j < 8; ++j) {
                hv[j] = fmaxf(p[j] * scb[cb + j] + shb[cb + j], 0.f);
                p[j] = hv[j];  // write normalized h back for k_gruxt
            }
            ah[kh] = pack8(hv);
        }
    }
    f32x4 acc[4];
#pragma unroll
    for (int t = 0; t < 4; ++t) acc[t] = (f32x4){0.f, 0.f, 0.f, 0.f};
#pragma unroll
    for (int kh = 0; kh < 2; ++kh) {
#pragma unroll
        for (int t = 0; t < 4; ++t) {
            bf16x8 b = *(const bf16x8*)(cwb + (t * 16 + mrow) * 64 + kh * 32 + q * 8);
            acc[t] = __builtin_amdgcn_mfma_f32_16x16x32_bf16(ah[kh], b, acc[t], 0, 0, 0);
        }
    }
    float sd[4] = {0, 0, 0, 0}, ss[4] = {0, 0, 0, 0};
#pragma unroll
    for (int t = 0; t < 4; ++t) {
        int j = t * 16 + mrow;
        float ad = att_dst[j], as = att_src[j];
#pragma unroll
        for (int r = 0; r < 4; ++r) {
            float v = acc[t][r];
            xt[(nb16 + q * 4 + r) * 64 + j] = f2b(v);
            sd[r] += v * ad;
            ss[r] += v * as;
        }
    }
#pragma unroll
    for (int off = 1; off < 16; off <<= 1) {
#pragma unroll
        for (int r = 0; r < 4; ++r) {
            sd[r] += __shfl_xor(sd[r], off);
            ss[r] += __shfl_xor(ss[r], off);
        }
    }
    if (mrow == 0) {
#pragma unroll
        for (int r = 0; r < 4; ++r) {
            adst[nb16 + q * 4 + r] = sd[r];
            asrc[nb16 + q * 4 + r] = ss[r];
        }
    }
}

// -------- single-pass segment softmax + aggregation; 4B pk entries; bf16 m out
// (round-0 proven version: LDS broadcast + per-edge asrc gather — the in-register
//  asrc variant cost 8x more __expf and regressed ~5us/launch, reverted)
__global__ __launch_bounds__(256) void k_agg(const int* __restrict__ rs,
                                             const uint_t* __restrict__ pk,
                                             const float* __restrict__ adst,
                                             const float* __restrict__ asrc,
                                             const ushort_t* __restrict__ xt,
                                             ushort_t* __restrict__ m, int n) {
    __shared__ float s_w[4][64];
    __shared__ int s_s[4][64];
    int lane = threadIdx.x & 63;
    int wv = threadIdx.x >> 6;
    int v = blockIdx.x * 4 + wv;
    if (v >= n) return;
    int start = rs[v], end = rs[v + 1];
    if (start >= end) {
        m[v * 64 + lane] = 0;
        return;
    }
    float adv = adst[v];
    int g = lane >> 3;        // edge sub-slot 0..7
    int cb = (lane & 7) * 8;  // channel base
    float acc[8] = {0, 0, 0, 0, 0, 0, 0, 0};
    float dsum = 0.f;
    for (int base = start; base < end; base += 64) {
        int e = base + lane;
        float w = 0.f;
        int s = 0;
        if (e < end) {
            uint_t p = pk[e];
            s = (int)(p & 0xFFFFu);
            float l = adv + asrc[s] + bfu((ushort_t)(p >> 16));
            l = (l >= 0.f) ? l : 0.2f * l;
            w = __expf(l);
        }
        dsum += w;
        s_w[wv][lane] = w;
        s_s[wv][lane] = s;
        int cnt = min(64, end - base);
        int nb8 = (cnt + 7) >> 3;
        for (int tb = 0; tb < nb8; ++tb) {
            int sl = tb * 8 + g;
            float w8 = s_w[wv][sl];
            int s8 = s_s[wv][sl];
            uint4 qv = *(const uint4*)(xt + s8 * 64 + cb);
            acc[0] += w8 * __uint_as_float(qv.x << 16);
            acc[1] += w8 * __uint_as_float(qv.x & 0xFFFF0000u);
            acc[2] += w8 * __uint_as_float(qv.y << 16);
            acc[3] += w8 * __uint_as_float(qv.y & 0xFFFF0000u);
            acc[4] += w8 * __uint_as_float(qv.z << 16);
            acc[5] += w8 * __uint_as_float(qv.z & 0xFFFF0000u);
            acc[6] += w8 * __uint_as_float(qv.w << 16);
            acc[7] += w8 * __uint_as_float(qv.w & 0xFFFF0000u);
        }
    }
#pragma unroll
    for (int off = 32; off; off >>= 1) dsum += __shfl_xor(dsum, off);
#pragma unroll
    for (int off = 8; off < 64; off <<= 1) {
#pragma unroll
        for (int j = 0; j < 8; ++j) acc[j] += __shfl_xor(acc[j], off);
    }
    float inv = 1.0f / fmaxf(dsum, 1e-20f);
    if (g == 0) {
        uint4 o;
        o.x = (uint_t)f2b(fmaxf(acc[0] * inv, 0.f)) |
              ((uint_t)f2b(fmaxf(acc[1] * inv, 0.f)) << 16);
        o.y = (uint_t)f2b(fmaxf(acc[2] * inv, 0.f)) |
              ((uint_t)f2b(fmaxf(acc[3] * inv, 0.f)) << 16);
        o.z = (uint_t)f2b(fmaxf(acc[4] * inv, 0.f)) |
              ((uint_t)f2b(fmaxf(acc[5] * inv, 0.f)) << 16);
        o.w = (uint_t)f2b(fmaxf(acc[6] * inv, 0.f)) |
              ((uint_t)f2b(fmaxf(acc[7] * inv, 0.f)) << 16);
        *(uint4*)(m + v * 64 + cb) = o;
    }
}

// -------- fused GRU + next-step xt: weights in padded LDS, 2 tiles per wave.
// 391 blocks (< 512 = 2-block/CU LDS-cap capacity): ALL blocks co-resident from
// t=0 — eliminates the second occupancy-wave and halves staging traffic+barriers.
// Per-tile body unchanged from the proven round-0 source; sequential tile loop
// with unroll 1 so registers are reused (no pressure doubling).
__global__ __launch_bounds__(256) void k_gruxt(
    const ushort_t* __restrict__ mb, float* __restrict__ h,
    const ushort_t* __restrict__ wb, const ushort_t* __restrict__ cwb,
    const float* __restrict__ b_ih, const float* __restrict__ b_hh,
    const float* __restrict__ att_dst, const float* __restrict__ att_src,
    int do_xt, ushort_t* __restrict__ xt, float* __restrict__ adst,
    float* __restrict__ asrc, int n) {
    __shared__ ushort_t swb[384 * WPAD];  // 55,296 B
    __shared__ ushort_t scw[64 * WPAD];   // 9,216 B -> 64,512 B total
    {
        const uint2* src = (const uint2*)wb;  // 4 ushorts per uint2
        for (int g = threadIdx.x; g < 6144; g += 256) {
            uint2 v = src[g];
            int row = g >> 4;
            int col = (g & 15) * 4;
            *(uint2*)(swb + row * WPAD + col) = v;
        }
        const uint2* srcc = (const uint2*)cwb;
        for (int g = threadIdx.x; g < 1024; g += 256) {
            uint2 v = srcc[g];
            int row = g >> 4;
            int col = (g & 15) * 4;
            *(uint2*)(scw + row * WPAD + col) = v;
        }
    }
    __syncthreads();
    int lane = threadIdx.x & 63;
    int wv = threadIdx.x >> 6;
    int mrow = lane & 15, q = lane >> 4;
#pragma unroll 1
    for (int u = 0; u < 2; ++u) {
        int tile = blockIdx.x * 8 + wv * 2 + u;
        if (tile * 16 >= n) break;
        int nb16 = tile * 16;
        // prefetch epilogue h (C-layout positions) early — latency hidden by MFMAs
        float hp[4][4];
#pragma unroll
        for (int t = 0; t < 4; ++t)
#pragma unroll
            for (int r = 0; r < 4; ++r)
                hp[t][r] = h[(nb16 + q * 4 + r) * 64 + t * 16 + mrow];
        bf16x8 am[2], ah[2];
        {
            const ushort_t* mp = mb + (nb16 + mrow) * 64 + q * 8;
            am[0] = *(const bf16x8*)(mp);
            am[1] = *(const bf16x8*)(mp + 32);
            const float* hpt = h + (nb16 + mrow) * 64 + q * 8;
            float hv[8];
#pragma unroll
            for (int j = 0; j < 8; ++j) hv[j] = hpt[j];
            ah[0] = pack8(hv);
#pragma unroll
            for (int j = 0; j < 8; ++j) hv[j] = hpt[32 + j];
            ah[1] = pack8(hv);
        }
        f32x4 acc[24];
#pragma unroll
        for (int t = 0; t < 24; ++t) acc[t] = (f32x4){0.f, 0.f, 0.f, 0.f};
#pragma unroll
        for (int kh = 0; kh < 2; ++kh) {
#pragma unroll
            for (int t = 0; t < 12; ++t) {
                bf16x8 b =
                    *(const bf16x8*)(swb + (t * 16 + mrow) * WPAD + kh * 32 + q * 8);
                acc[t] =
                    __builtin_amdgcn_mfma_f32_16x16x32_bf16(am[kh], b, acc[t], 0, 0, 0);
            }
#pragma unroll
            for (int t = 0; t < 12; ++t) {
                bf16x8 b = *(const bf16x8*)(swb + (192 + t * 16 + mrow) * WPAD +
                                            kh * 32 + q * 8);
                acc[12 + t] = __builtin_amdgcn_mfma_f32_16x16x32_bf16(ah[kh], b,
                                                                      acc[12 + t], 0, 0, 0);
            }
        }
#pragma unroll
        for (int t = 0; t < 4; ++t) {
            int j = t * 16 + mrow;
            float bir = b_ih[j], biz = b_ih[64 + j], bin = b_ih[128 + j];
            float bhr = b_hh[j], bhz = b_hh[64 + j], bhn = b_hh[128 + j];
#pragma unroll
            for (int r = 0; r < 4; ++r) {
                int node = nb16 + q * 4 + r;
                float gr = acc[t][r] + bir + acc[12 + t][r] + bhr;
                float gz = acc[4 + t][r] + biz + acc[16 + t][r] + bhz;
                float rr = sigm(gr);
                float zz = sigm(gz);
                float tt = acc[8 + t][r] + bin + rr * (acc[20 + t][r] + bhn);
                h[node * 64 + j] = (1.f - zz) * tanh_f(tt) + zz * hp[t][r];
            }
        }
        if (do_xt) {
            __threadfence_block();  // drain wave's h stores (lockstep ordering)
            // reload new h in A-layout (same 16 nodes, just written — L1/L2 hit)
            bf16x8 ah2[2];
            {
                const float* hpt = h + (nb16 + mrow) * 64 + q * 8;
                float hv[8];
#pragma unroll
                for (int j = 0; j < 8; ++j) hv[j] = hpt[j];
                ah2[0] = pack8(hv);
#pragma unroll
                for (int j = 0; j < 8; ++j) hv[j] = hpt[32 + j];
                ah2[1] = pack8(hv);
            }
            f32x4 xacc[4];
#pragma unroll
            for (int t = 0; t < 4; ++t) xacc[t] = (f32x4){0.f, 0.f, 0.f, 0.f};
#pragma unroll
            for (int kh = 0; kh < 2; ++kh) {
#pragma unroll
                for (int t = 0; t < 4; ++t) {
                    bf16x8 b =
                        *(const bf16x8*)(scw + (t * 16 + mrow) * WPAD + kh * 32 + q * 8);
                    xacc[t] = __builtin_amdgcn_mfma_f32_16x16x32_bf16(ah2[kh], b,
                                                                      xacc[t], 0, 0, 0);
                }
            }
            float sd[4] = {0, 0, 0, 0}, ss[4] = {0, 0, 0, 0};
#pragma unroll
            for (int t = 0; t < 4; ++t) {
                int j = t * 16 + mrow;
                float ad = att_dst[j], as = att_src[j];
#pragma unroll
                for (int r = 0; r < 4; ++r) {
                    float v = xacc[t][r];
                    xt[(nb16 + q * 4 + r) * 64 + j] = f2b(v);
                    sd[r] += v * ad;
                    ss[r] += v * as;
                }
            }
#pragma unroll
            for (int off = 1; off < 16; off <<= 1) {
#pragma unroll
                for (int r = 0; r < 4; ++r) {
                    sd[r] += __shfl_xor(sd[r], off);
                    ss[r] += __shfl_xor(ss[r], off);
                }
            }
            if (mrow == 0) {
#pragma unroll
                for (int r = 0; r < 4; ++r) {
                    adst[nb16 + q * 4 + r] = sd[r];
                    asrc[nb16 + q * 4 + r] = ss[r];
                }
            }
        }
    }
}

// -------- out = x @ lin_w + lin_b + h via MFMA (K=128, f32 x in-reg cast)
__global__ __launch_bounds__(256) void k_out(const float* __restrict__ x,
                                             const ushort_t* __restrict__ linT,
                                             const float* __restrict__ lin_b,
                                             const float* __restrict__ h,
                                             float* __restrict__ out, int n) {
    int lane = threadIdx.x & 63;
    int wv = threadIdx.x >> 6;
    int tile = blockIdx.x * 4 + wv;
    if (tile * 16 >= n) return;
    int nb16 = tile * 16;
    int mrow = lane & 15, q = lane >> 4;
    const float* xp = x + (nb16 + mrow) * 128 + q * 8;
    bf16x8 a[4];
#pragma unroll
    for (int kc = 0; kc < 4; ++kc) {
        float hv[8];
        const float* p = xp + kc * 32;
#pragma unroll
        for (int j = 0; j < 8; ++j) hv[j] = p[j];
        a[kc] = pack8(hv);
    }
    f32x4 acc[4];
#pragma unroll
    for (int t = 0; t < 4; ++t) acc[t] = (f32x4){0.f, 0.f, 0.f, 0.f};
#pragma unroll
    for (int kc = 0; kc < 4; ++kc) {
#pragma unroll
        for (int t = 0; t < 4; ++t) {
            bf16x8 b = *(const bf16x8*)(linT + (t * 16 + mrow) * 128 + kc * 32 + q * 8);
            acc[t] = __builtin_amdgcn_mfma_f32_16x16x32_bf16(a[kc], b, acc[t], 0, 0, 0);
        }
    }
#pragma unroll
    for (int t = 0; t < 4; ++t) {
        int j = t * 16 + mrow;
        float bias = lin_b[j];
#pragma unroll
        for (int r = 0; r < 4; ++r) {
            int node = nb16 + q * 4 + r;
            out[node * 64 + j] = acc[t][r] + bias + h[node * 64 + j];
        }
    }
}

extern "C" void kernel_launch(void* const* d_in, const int* in_sizes, int n_in,
                              void* d_out, int out_size, void* d_ws, size_t ws_size,
                              hipStream_t stream) {
    const float* x = (const float*)d_in[0];
    const float* edge_attr = (const float*)d_in[1];
    const float* mlp_w = (const float*)d_in[2];
    const float* mlp_b = (const float*)d_in[3];
    const float* bn_g = (const float*)d_in[4];
    const float* bn_b = (const float*)d_in[5];
    const float* conv_w = (const float*)d_in[6];
    const float* att_dst = (const float*)d_in[7];
    const float* att_src = (const float*)d_in[8];
    const float* att_edge = (const float*)d_in[9];
    const float* w_ih = (const float*)d_in[10];
    const float* w_hh = (const float*)d_in[11];
    const float* b_ih = (const float*)d_in[12];
    const float* b_hh = (const float*)d_in[13];
    const float* lin_w = (const float*)d_in[14];
    const float* lin_b = (const float*)d_in[15];
    const int* ei = (const int*)d_in[16];

    char* ws = (char*)d_ws;
    float* f_h = (float*)(ws + 0);                // 12,800,000
    ushort_t* mb = (ushort_t*)(ws + 12800000);    // 6,400,000
    ushort_t* xt = (ushort_t*)(ws + 19200000);    // 6,400,000
    uint2* bkt = (uint2*)(ws + 25600000);         // 14,413,824 slack buckets
    uint_t* pk = (uint_t*)(ws + 40013824);        // 6,400,000 dense 4B entries
    float* f_adst = (float*)(ws + 46413824);      // 200,192
    float* f_asrc = (float*)(ws + 46614016);      // 200,192
    int* row_start = (int*)(ws + 46814208);       // 200,448 (n+1)
    float* stats = (float*)(ws + 47014656);       // 32,768 (128 slots, 256B stride)
    int* flag = (int*)(ws + 47047424);            // 512
    ushort_t* wb = (ushort_t*)(ws + 47047936);    // 49,152
    ushort_t* cwb = (ushort_t*)(ws + 47097088);   // 8,192
    ushort_t* mlpT = (ushort_t*)(ws + 47105280);  // 16,384
    ushort_t* linT = (ushort_t*)(ws + 47121664);  // 16,384
    int* gtail = (int*)(ws + 47138048);           // 100,096 (391 slots, 256B stride)

    const size_t needed = 47238144;
    if (ws_size < needed) {
        k_sentinel<<<(out_size + 255) / 256, 256, 0, stream>>>((float*)d_out, out_size);
        return;
    }

    const int n = N_NODES, e = N_EDGES;
    const int gT = ((n + 15) / 16 + 3) / 4;   // 782 (4-tile MFMA kernels)
    const int gT8 = ((n + 15) / 16 + 7) / 8;  // 391 (k_gruxt: 8 tiles/block)
    const int gN4 = (n + 3) / 4;              // 12500
    const int gPrep = 176 + 1 + (NB_BKT + 255) / 256;  // 179
    const float inv_n = 1.0f / (float)n;

    hipMemsetAsync(stats, 0, 32768, stream);

    k_prep<<<gPrep, 256, 0, stream>>>(w_ih, w_hh, conv_w, mlp_w, lin_w, ei, wb, cwb,
                                      mlpT, linT, flag, gtail);
    // bucket-append (782 blocks) || emb MFMA (782 blocks) in one dispatch
    k_embbkt<<<GBK + gT, 256, 0, stream>>>(ei, flag, edge_attr, att_edge, gtail, bkt, e,
                                           x, mlpT, mlp_b, f_h, n);
    // sortb (391 blocks) || BN stats (256 blocks) in one dispatch
    k_statsort<<<NB_BKT + 256, 256, 0, stream>>>(gtail, bkt, pk, row_start, n, f_h,
                                                 stats);
    // step-0 xt with fused BN+ReLU
    k_xt<<<gT, 256, 0, stream>>>(f_h, cwb, att_dst, att_src, bn_g, bn_b, stats, inv_n,
                                 xt, f_adst, f_asrc, n);

    for (int s = 0; s < 3; ++s) {
        k_agg<<<gN4, 256, 0, stream>>>(row_start, pk, f_adst, f_asrc, xt, mb, n);
        k_gruxt<<<gT8, 256, 0, stream>>>(mb, f_h, wb, cwb, b_ih, b_hh, att_dst, att_src,
                                         (s < 2) ? 1 : 0, xt, f_adst, f_asrc, n);
    }

    k_out<<<gT, 256, 0, stream>>>(x, linT, lin_b, f_h, (float*)d_out, n);
}

// Round 8
// 367.356 us; speedup vs baseline: 1.0473x; 1.0433x over previous
//
#include <hip/hip_runtime.h>

typedef unsigned short ushort_t;
typedef unsigned int uint_t;
typedef __attribute__((ext_vector_type(8))) short bf16x8;
typedef __attribute__((ext_vector_type(4))) float f32x4;

#define N_NODES 50000
#define N_EDGES 1600000
#define NB_BKT 391    // dst buckets of 128 nodes
#define CAP_BKT 4608  // slack capacity per bucket (mean 4096, +8 sigma)
#define CAP_B 6144    // LDS staging entries per bucket in sortb phase
#define GBK 782       // bucket-append blocks (2048 edges each, 8/thread — proven)
#define WPAD 72       // LDS row stride (ushorts): uniform bank spread for b128 reads
#define APAD 64       // atomic-target padding (ints/floats): one per 256B channel line
// D = 64, IN = 128, ED = 3, H = 1, STEPS = 3. Inputs f32; edge_index int32/int64.

__device__ __forceinline__ float bfu(ushort_t u) {
    return __uint_as_float(((uint_t)u) << 16);
}
__device__ __forceinline__ ushort_t f2b(float f) {
    uint_t x = __float_as_uint(f);
    uint_t r = (x + 0x7FFFu + ((x >> 16) & 1u)) >> 16;
    return (ushort_t)r;
}
__device__ __forceinline__ float sigm(float x) {
    return 1.0f / (1.0f + __expf(-x));
}
__device__ __forceinline__ float tanh_f(float x) {
    return 1.0f - 2.0f / (__expf(2.0f * x) + 1.0f);
}
__device__ __forceinline__ bf16x8 pack8(const float* v) {
    bf16x8 r;
#pragma unroll
    for (int j = 0; j < 8; ++j) r[j] = (short)f2b(v[j]);
    return r;
}
__device__ __forceinline__ int ld_src(const int* __restrict__ ei, int i, int f64) {
    return f64 ? ei[2 * i] : ei[i];
}
__device__ __forceinline__ int ld_dst(const int* __restrict__ ei, int i, int f64) {
    return f64 ? ei[2 * N_EDGES + 2 * i] : ei[N_EDGES + i];
}
__device__ __forceinline__ bool is_f64(const int* flag) { return flag[0] > 2048; }

// -------- ws-too-small sentinel
__global__ void k_sentinel(float* __restrict__ out, int n) {
    int i = blockIdx.x * 256 + threadIdx.x;
    if (i < n) out[i] = 100.0f;
}

// -------- merged prep: weights bf16 repack (blk<176), edge-dtype probe (blk==176),
//          gtail init (blk>=177; gtail padded to 256B stride per bucket)
__global__ void k_prep(const float* __restrict__ w_ih, const float* __restrict__ w_hh,
                       const float* __restrict__ conv_w, const float* __restrict__ mlp_w,
                       const float* __restrict__ lin_w, const int* __restrict__ ei,
                       ushort_t* __restrict__ wb, ushort_t* __restrict__ cwb,
                       ushort_t* __restrict__ mlpT, ushort_t* __restrict__ linT,
                       int* __restrict__ flag, int* __restrict__ gtail) {
    int blk = blockIdx.x;
    if (blk < 176) {
        int t = blk * 256 + threadIdx.x;
        if (t < 24576) {
            const float* w = (t < 12288) ? w_ih : w_hh;
            wb[t] = f2b(w[t < 12288 ? t : t - 12288]);
        } else if (t < 28672) {
            int r = t - 24576;
            int j = r >> 6, k = r & 63;
            cwb[j * 64 + k] = f2b(conv_w[k * 64 + j]);
        } else if (t < 36864) {
            int r = t - 28672;
            int j = r >> 7, k = r & 127;
            mlpT[j * 128 + k] = f2b(mlp_w[k * 64 + j]);
        } else if (t < 45056) {
            int r = t - 36864;
            int j = r >> 7, k = r & 127;
            linT[j * 128 + k] = f2b(lin_w[k * 64 + j]);
        }
    } else if (blk == 176) {
        __shared__ int red[256];
        int tid = threadIdx.x;
        int zeros = 0;
#pragma unroll
        for (int j = 0; j < 16; ++j) {
            int slot = (tid * 16 + j) * 2 + 1;  // odd int32 slots, in-bounds either way
            if (ei[slot] == 0) zeros++;
        }
        red[tid] = zeros;
        __syncthreads();
        for (int off = 128; off; off >>= 1) {
            if (tid < off) red[tid] += red[tid + off];
            __syncthreads();
        }
        if (tid == 0) flag[0] = red[0];  // direct store, no pre-zero needed
    } else {
        int b = (blk - 177) * 256 + threadIdx.x;
        if (b < NB_BKT) gtail[b * APAD] = b * CAP_BKT;
    }
}

// -------- merged: bucket-append (blocks [0,GBK)) || emb MFMA (blocks [GBK, GBK+gT))
__global__ __launch_bounds__(256) void k_embbkt(
    const int* __restrict__ ei, const int* __restrict__ flag,
    const float* __restrict__ ea, const float* __restrict__ ae,
    int* __restrict__ gtail, uint2* __restrict__ bkt, int e,
    const float* __restrict__ x, const ushort_t* __restrict__ mlpT,
    const float* __restrict__ mlp_b, float* __restrict__ h0, int n) {
    if (blockIdx.x < GBK) {
        // ---- bucket append: entry p.x = src | (dst&127)<<16 ; p.y = sel f32 bits
        __shared__ int cnt[NB_BKT];
        __shared__ int gbase[NB_BKT];
        for (int i = threadIdx.x; i < NB_BKT; i += 256) cnt[i] = 0;
        __syncthreads();
        int base = blockIdx.x * 2048;
        int f64 = is_f64(flag);
        float a0 = ae[0], a1 = ae[1], a2 = ae[2];
        uint_t w0[8], w1[8];
        int bk[8], rk[8];
#pragma unroll
        for (int j = 0; j < 8; ++j) {
            int i = base + j * 256 + threadIdx.x;
            bk[j] = -1;
            if (i < e) {
                int d = ld_dst(ei, i, f64);
                if ((uint_t)d < (uint_t)N_NODES) {
                    int s = ld_src(ei, i, f64);
                    if ((uint_t)s >= (uint_t)N_NODES) s = 0;
                    float ed = ea[i * 3] * a0 + ea[i * 3 + 1] * a1 + ea[i * 3 + 2] * a2;
                    bk[j] = d >> 7;
                    w0[j] = (uint_t)s | ((uint_t)(d & 127) << 16);
                    w1[j] = __float_as_uint(ed);
                    rk[j] = atomicAdd(&cnt[bk[j]], 1);
                }
            }
        }
        __syncthreads();
        for (int t = threadIdx.x; t < NB_BKT; t += 256) {
            int c = cnt[t];
            gbase[t] = c ? atomicAdd(&gtail[t * APAD], c) : 0;
        }
        __syncthreads();
#pragma unroll
        for (int j = 0; j < 8; ++j) {
            if (bk[j] >= 0) {
                int pos = gbase[bk[j]] + rk[j];
                if (pos < (bk[j] + 1) * CAP_BKT) {  // drop on impossible overflow
                    uint2 p;
                    p.x = w0[j];
                    p.y = w1[j];
                    bkt[pos] = p;
                }
            }
        }
    } else {
        // ---- h0 = x @ mlp_w + mlp_b via MFMA, 16 nodes/wave (K=128)
        int lane = threadIdx.x & 63;
        int wv = threadIdx.x >> 6;
        int tile = (blockIdx.x - GBK) * 4 + wv;
        if (tile * 16 >= n) return;
        int nb16 = tile * 16;
        int mrow = lane & 15, q = lane >> 4;
        const float* xp = x + (nb16 + mrow) * 128 + q * 8;
        bf16x8 a[4];
#pragma unroll
        for (int kc = 0; kc < 4; ++kc) {
            float hv[8];
            const float* p = xp + kc * 32;
#pragma unroll
            for (int j = 0; j < 8; ++j) hv[j] = p[j];
            a[kc] = pack8(hv);
        }
        f32x4 acc[4];
#pragma unroll
        for (int t = 0; t < 4; ++t) acc[t] = (f32x4){0.f, 0.f, 0.f, 0.f};
#pragma unroll
        for (int kc = 0; kc < 4; ++kc) {
#pragma unroll
            for (int t = 0; t < 4; ++t) {
                bf16x8 b =
                    *(const bf16x8*)(mlpT + (t * 16 + mrow) * 128 + kc * 32 + q * 8);
                acc[t] = __builtin_amdgcn_mfma_f32_16x16x32_bf16(a[kc], b, acc[t], 0, 0, 0);
            }
        }
#pragma unroll
        for (int t = 0; t < 4; ++t) {
            int j = t * 16 + mrow;
            float bias = mlp_b[j];
#pragma unroll
            for (int r = 0; r < 4; ++r)
                h0[(nb16 + q * 4 + r) * 64 + j] = acc[t][r] + bias;
        }
    }
}

// -------- merged: sortb (blocks [0,NB_BKT)) || BN stats (blocks [NB_BKT, NB_BKT+256))
__global__ __launch_bounds__(256) void k_statsort(
    const int* __restrict__ gtail, const uint2* __restrict__ bkt,
    uint_t* __restrict__ pk, int* __restrict__ rs, int n,
    const float* __restrict__ h0, float* __restrict__ stats) {
    __shared__ char smem[26624];
    int tid = threadIdx.x;
    if (blockIdx.x < NB_BKT) {
        int* red = (int*)smem;                 // 256 ints
        int* cnt = (int*)(smem + 1024);        // 128 ints
        int* sc = (int*)(smem + 1536);         // 128 ints
        uint_t* stg = (uint_t*)(smem + 2048);  // CAP_B uints (24 KiB)
        int b = blockIdx.x;
        int partial = 0;
        for (int i = tid; i < b; i += 256)
            partial += min(gtail[i * APAD] - i * CAP_BKT, CAP_BKT);
        red[tid] = partial;
        __syncthreads();
        for (int off = 128; off; off >>= 1) {
            if (tid < off) red[tid] += red[tid + off];
            __syncthreads();
        }
        int obase = red[0];
        int node0 = b * 128;
        int nloc = min(128, n - node0);
        int size = min(gtail[b * APAD] - b * CAP_BKT, CAP_BKT);
        const uint2* bin = bkt + b * CAP_BKT;
        for (int i = tid; i < 128; i += 256) cnt[i] = 0;
        __syncthreads();
        for (int ofs = tid; ofs < size; ofs += 256) {
            int dlow = (bin[ofs].x >> 16) & 127;
            atomicAdd(&cnt[dlow], 1);
        }
        __syncthreads();
        if (tid < 128) sc[tid] = cnt[tid];
        __syncthreads();
        for (int off = 1; off < 128; off <<= 1) {
            int add = (tid < 128 && tid >= off) ? sc[tid - off] : 0;
            __syncthreads();
            if (tid < 128) sc[tid] += add;
            __syncthreads();
        }
        if (tid < 128) sc[tid] -= cnt[tid];  // exclusive
        __syncthreads();
        if (tid < nloc) rs[node0 + tid] = obase + sc[tid];
        if (b == NB_BKT - 1 && tid == 0) rs[n] = obase + size;
        for (int i = tid; i < 128; i += 256) cnt[i] = 0;
        __syncthreads();
        for (int ofs = tid; ofs < size; ofs += 256) {
            uint2 p = bin[ofs];
            int dlow = (p.x >> 16) & 127;
            int r = atomicAdd(&cnt[dlow], 1);
            int pos = sc[dlow] + r;
            uint_t q = (p.x & 0xFFFFu) | ((uint_t)f2b(__uint_as_float(p.y)) << 16);
            if (pos < CAP_B) stg[pos] = q;
            else pk[obase + pos] = q;  // statistically impossible overflow fallback
        }
        __syncthreads();
        int wlim = min(size, CAP_B);
        for (int ofs = tid; ofs < wlim; ofs += 256) pk[obase + ofs] = stg[ofs];
    } else {
        float* ssum = (float*)smem;          // 256 floats
        float* ssq = (float*)(smem + 1024);  // 256 floats
        int gid = (blockIdx.x - NB_BKT) * 256 + tid;
        int col = gid & 63;
        int rg = gid >> 6;
        float s = 0.f, s2 = 0.f;
        for (int row = rg; row < n; row += 1024) {
            float v = h0[row * 64 + col];
            s += v;
            s2 += v * v;
        }
        ssum[tid] = s;
        ssq[tid] = s2;
        __syncthreads();
        if (tid < 64) {
            s = ssum[tid] + ssum[tid + 64] + ssum[tid + 128] + ssum[tid + 192];
            s2 = ssq[tid] + ssq[tid + 64] + ssq[tid + 128] + ssq[tid + 192];
            atomicAdd(&stats[tid * APAD], s);
            atomicAdd(&stats[(64 + tid) * APAD], s2);
        }
    }
}

// -------- step-0 xt = h @ conv_w via MFMA, with fused BN+ReLU (normalizes h in place)
__global__ __launch_bounds__(256) void k_xt(float* __restrict__ h,
                                            const ushort_t* __restrict__ cwb,
                                            const float* __restrict__ att_dst,
                                            const float* __restrict__ att_src,
                                            const float* __restrict__ bn_g,
                                            const float* __restrict__ bn_b,
                                            const float* __restrict__ stats,
                                            float inv_n,
                                            ushort_t* __restrict__ xt,
                                            float* __restrict__ adst,
                                            float* __restrict__ asrc, int n) {
    __shared__ float scb[64], shb[64];
    {
        int tid = threadIdx.x;
        if (tid < 64) {
            float mu = stats[tid * APAD] * inv_n;
            float var = fmaxf(stats[(64 + tid) * APAD] * inv_n - mu * mu, 0.f);
            float sc = rsqrtf(var + 1e-5f) * bn_g[tid];
            scb[tid] = sc;
            shb[tid] = bn_b[tid] - mu * sc;
        }
        __syncthreads();
    }
    int lane = threadIdx.x & 63;
    int wv = threadIdx.x >> 6;
    int tile = blockIdx.x * 4 + wv;
    if (tile * 16 >= n) return;
    int nb16 = tile * 16;
    int mrow = lane & 15, q = lane >> 4;
    bf16x8 ah[2];
    {
        float* hp = h + (nb16 + mrow) * 64 + q * 8;
        float hv[8];
#pragma unroll
        for (int kh = 0; kh < 2; ++kh) {
            float* p = hp + kh * 32;
            int cb = kh * 32 + q * 8;
#pragma unroll
            for (int j = 0; j < 8; ++j) {
                hv[j] = fmaxf(p[j] * scb[cb + j] + shb[cb + j], 0.f);
                p[j] = hv[j];  // write normalized h back for k_gruxt
            }
            ah[kh] = pack8(hv);
        }
    }
    f32x4 acc[4];
#pragma unroll
    for (int t = 0; t < 4; ++t) acc[t] = (f32x4){0.f, 0.f, 0.f, 0.f};
#pragma unroll
    for (int kh = 0; kh < 2; ++kh) {
#pragma unroll
        for (int t = 0; t < 4; ++t) {
            bf16x8 b = *(const bf16x8*)(cwb + (t * 16 + mrow) * 64 + kh * 32 + q * 8);
            acc[t] = __builtin_amdgcn_mfma_f32_16x16x32_bf16(ah[kh], b, acc[t], 0, 0, 0);
        }
    }
    float sd[4] = {0, 0, 0, 0}, ss[4] = {0, 0, 0, 0};
#pragma unroll
    for (int t = 0; t < 4; ++t) {
        int j = t * 16 + mrow;
        float ad = att_dst[j], as = att_src[j];
#pragma unroll
        for (int r = 0; r < 4; ++r) {
            float v = acc[t][r];
            xt[(nb16 + q * 4 + r) * 64 + j] = f2b(v);
            sd[r] += v * ad;
            ss[r] += v * as;
        }
    }
#pragma unroll
    for (int off = 1; off < 16; off <<= 1) {
#pragma unroll
        for (int r = 0; r < 4; ++r) {
            sd[r] += __shfl_xor(sd[r], off);
            ss[r] += __shfl_xor(ss[r], off);
        }
    }
    if (mrow == 0) {
#pragma unroll
        for (int r = 0; r < 4; ++r) {
            adst[nb16 + q * 4 + r] = sd[r];
            asrc[nb16 + q * 4 + r] = ss[r];
        }
    }
}

// -------- single-pass segment softmax + aggregation; 4B pk entries; bf16 m out
__global__ __launch_bounds__(256) void k_agg(const int* __restrict__ rs,
                                             const uint_t* __restrict__ pk,
                                             const float* __restrict__ adst,
                                             const float* __restrict__ asrc,
                                             const ushort_t* __restrict__ xt,
                                             ushort_t* __restrict__ m, int n) {
    __shared__ float s_w[4][64];
    __shared__ int s_s[4][64];
    int lane = threadIdx.x & 63;
    int wv = threadIdx.x >> 6;
    int v = blockIdx.x * 4 + wv;
    if (v >= n) return;
    int start = rs[v], end = rs[v + 1];
    if (start >= end) {
        m[v * 64 + lane] = 0;
        return;
    }
    float adv = adst[v];
    int g = lane >> 3;        // edge sub-slot 0..7
    int cb = (lane & 7) * 8;  // channel base
    float acc[8] = {0, 0, 0, 0, 0, 0, 0, 0};
    float dsum = 0.f;
    for (int base = start; base < end; base += 64) {
        int e = base + lane;
        float w = 0.f;
        int s = 0;
        if (e < end) {
            uint_t p = pk[e];
            s = (int)(p & 0xFFFFu);
            float l = adv + asrc[s] + bfu((ushort_t)(p >> 16));
            l = (l >= 0.f) ? l : 0.2f * l;
            w = __expf(l);
        }
        dsum += w;
        s_w[wv][lane] = w;
        s_s[wv][lane] = s;
        int cnt = min(64, end - base);
        int nb8 = (cnt + 7) >> 3;
        for (int tb = 0; tb < nb8; ++tb) {
            int sl = tb * 8 + g;
            float w8 = s_w[wv][sl];
            int s8 = s_s[wv][sl];
            uint4 qv = *(const uint4*)(xt + s8 * 64 + cb);
            acc[0] += w8 * __uint_as_float(qv.x << 16);
            acc[1] += w8 * __uint_as_float(qv.x & 0xFFFF0000u);
            acc[2] += w8 * __uint_as_float(qv.y << 16);
            acc[3] += w8 * __uint_as_float(qv.y & 0xFFFF0000u);
            acc[4] += w8 * __uint_as_float(qv.z << 16);
            acc[5] += w8 * __uint_as_float(qv.z & 0xFFFF0000u);
            acc[6] += w8 * __uint_as_float(qv.w << 16);
            acc[7] += w8 * __uint_as_float(qv.w & 0xFFFF0000u);
        }
    }
#pragma unroll
    for (int off = 32; off; off >>= 1) dsum += __shfl_xor(dsum, off);
#pragma unroll
    for (int off = 8; off < 64; off <<= 1) {
#pragma unroll
        for (int j = 0; j < 8; ++j) acc[j] += __shfl_xor(acc[j], off);
    }
    float inv = 1.0f / fmaxf(dsum, 1e-20f);
    if (g == 0) {
        uint4 o;
        o.x = (uint_t)f2b(fmaxf(acc[0] * inv, 0.f)) |
              ((uint_t)f2b(fmaxf(acc[1] * inv, 0.f)) << 16);
        o.y = (uint_t)f2b(fmaxf(acc[2] * inv, 0.f)) |
              ((uint_t)f2b(fmaxf(acc[3] * inv, 0.f)) << 16);
        o.z = (uint_t)f2b(fmaxf(acc[4] * inv, 0.f)) |
              ((uint_t)f2b(fmaxf(acc[5] * inv, 0.f)) << 16);
        o.w = (uint_t)f2b(fmaxf(acc[6] * inv, 0.f)) |
              ((uint_t)f2b(fmaxf(acc[7] * inv, 0.f)) << 16);
        *(uint4*)(m + v * 64 + cb) = o;
    }
}

// -------- fused GRU + next-step xt: weights in padded LDS, 16 nodes/wave
// (round-0 proven structure: 1 tile/wave, 782 blocks — 2-tile variant cost
//  +4us/launch: serial second tile adds an unhidden latency chain per wave)
__global__ __launch_bounds__(256) void k_gruxt(
    const ushort_t* __restrict__ mb, float* __restrict__ h,
    const ushort_t* __restrict__ wb, const ushort_t* __restrict__ cwb,
    const float* __restrict__ b_ih, const float* __restrict__ b_hh,
    const float* __restrict__ att_dst, const float* __restrict__ att_src,
    int do_xt, ushort_t* __restrict__ xt, float* __restrict__ adst,
    float* __restrict__ asrc, int n) {
    __shared__ ushort_t swb[384 * WPAD];  // 55,296 B
    __shared__ ushort_t scw[64 * WPAD];   // 9,216 B -> 64,512 B total
    {
        const uint2* src = (const uint2*)wb;  // 4 ushorts per uint2
        for (int g = threadIdx.x; g < 6144; g += 256) {
            uint2 v = src[g];
            int row = g >> 4;
            int col = (g & 15) * 4;
            *(uint2*)(swb + row * WPAD + col) = v;
        }
        const uint2* srcc = (const uint2*)cwb;
        for (int g = threadIdx.x; g < 1024; g += 256) {
            uint2 v = srcc[g];
            int row = g >> 4;
            int col = (g & 15) * 4;
            *(uint2*)(scw + row * WPAD + col) = v;
        }
    }
    __syncthreads();
    int lane = threadIdx.x & 63;
    int wv = threadIdx.x >> 6;
    int tile = blockIdx.x * 4 + wv;
    if (tile * 16 >= n) return;
    int nb16 = tile * 16;
    int mrow = lane & 15, q = lane >> 4;
    // prefetch epilogue h (C-layout positions) early — latency hidden by MFMAs
    float hp[4][4];
#pragma unroll
    for (int t = 0; t < 4; ++t)
#pragma unroll
        for (int r = 0; r < 4; ++r)
            hp[t][r] = h[(nb16 + q * 4 + r) * 64 + t * 16 + mrow];
    bf16x8 am[2], ah[2];
    {
        const ushort_t* mp = mb + (nb16 + mrow) * 64 + q * 8;
        am[0] = *(const bf16x8*)(mp);
        am[1] = *(const bf16x8*)(mp + 32);
        const float* hpt = h + (nb16 + mrow) * 64 + q * 8;
        float hv[8];
#pragma unroll
        for (int j = 0; j < 8; ++j) hv[j] = hpt[j];
        ah[0] = pack8(hv);
#pragma unroll
        for (int j = 0; j < 8; ++j) hv[j] = hpt[32 + j];
        ah[1] = pack8(hv);
    }
    f32x4 acc[24];
#pragma unroll
    for (int t = 0; t < 24; ++t) acc[t] = (f32x4){0.f, 0.f, 0.f, 0.f};
#pragma unroll
    for (int kh = 0; kh < 2; ++kh) {
#pragma unroll
        for (int t = 0; t < 12; ++t) {
            bf16x8 b = *(const bf16x8*)(swb + (t * 16 + mrow) * WPAD + kh * 32 + q * 8);
            acc[t] = __builtin_amdgcn_mfma_f32_16x16x32_bf16(am[kh], b, acc[t], 0, 0, 0);
        }
#pragma unroll
        for (int t = 0; t < 12; ++t) {
            bf16x8 b =
                *(const bf16x8*)(swb + (192 + t * 16 + mrow) * WPAD + kh * 32 + q * 8);
            acc[12 + t] =
                __builtin_amdgcn_mfma_f32_16x16x32_bf16(ah[kh], b, acc[12 + t], 0, 0, 0);
        }
    }
#pragma unroll
    for (int t = 0; t < 4; ++t) {
        int j = t * 16 + mrow;
        float bir = b_ih[j], biz = b_ih[64 + j], bin = b_ih[128 + j];
        float bhr = b_hh[j], bhz = b_hh[64 + j], bhn = b_hh[128 + j];
#pragma unroll
        for (int r = 0; r < 4; ++r) {
            int node = nb16 + q * 4 + r;
            float gr = acc[t][r] + bir + acc[12 + t][r] + bhr;
            float gz = acc[4 + t][r] + biz + acc[16 + t][r] + bhz;
            float rr = sigm(gr);
            float zz = sigm(gz);
            float tt = acc[8 + t][r] + bin + rr * (acc[20 + t][r] + bhn);
            h[node * 64 + j] = (1.f - zz) * tanh_f(tt) + zz * hp[t][r];
        }
    }
    if (!do_xt) return;
    __threadfence_block();  // drain wave's h stores (lockstep => all 64 lanes ordered)
    // reload new h in A-layout (same 16 nodes, just written — L1/L2 hit)
    bf16x8 ah2[2];
    {
        const float* hpt = h + (nb16 + mrow) * 64 + q * 8;
        float hv[8];
#pragma unroll
        for (int j = 0; j < 8; ++j) hv[j] = hpt[j];
        ah2[0] = pack8(hv);
#pragma unroll
        for (int j = 0; j < 8; ++j) hv[j] = hpt[32 + j];
        ah2[1] = pack8(hv);
    }
    f32x4 xacc[4];
#pragma unroll
    for (int t = 0; t < 4; ++t) xacc[t] = (f32x4){0.f, 0.f, 0.f, 0.f};
#pragma unroll
    for (int kh = 0; kh < 2; ++kh) {
#pragma unroll
        for (int t = 0; t < 4; ++t) {
            bf16x8 b = *(const bf16x8*)(scw + (t * 16 + mrow) * WPAD + kh * 32 + q * 8);
            xacc[t] = __builtin_amdgcn_mfma_f32_16x16x32_bf16(ah2[kh], b, xacc[t], 0, 0, 0);
        }
    }
    float sd[4] = {0, 0, 0, 0}, ss[4] = {0, 0, 0, 0};
#pragma unroll
    for (int t = 0; t < 4; ++t) {
        int j = t * 16 + mrow;
        float ad = att_dst[j], as = att_src[j];
#pragma unroll
        for (int r = 0; r < 4; ++r) {
            float v = xacc[t][r];
            xt[(nb16 + q * 4 + r) * 64 + j] = f2b(v);
            sd[r] += v * ad;
            ss[r] += v * as;
        }
    }
#pragma unroll
    for (int off = 1; off < 16; off <<= 1) {
#pragma unroll
        for (int r = 0; r < 4; ++r) {
            sd[r] += __shfl_xor(sd[r], off);
            ss[r] += __shfl_xor(ss[r], off);
        }
    }
    if (mrow == 0) {
#pragma unroll
        for (int r = 0; r < 4; ++r) {
            adst[nb16 + q * 4 + r] = sd[r];
            asrc[nb16 + q * 4 + r] = ss[r];
        }
    }
}

// -------- out = x @ lin_w + lin_b + h via MFMA (K=128, f32 x in-reg cast)
__global__ __launch_bounds__(256) void k_out(const float* __restrict__ x,
                                             const ushort_t* __restrict__ linT,
                                             const float* __restrict__ lin_b,
                                             const float* __restrict__ h,
                                             float* __restrict__ out, int n) {
    int lane = threadIdx.x & 63;
    int wv = threadIdx.x >> 6;
    int tile = blockIdx.x * 4 + wv;
    if (tile * 16 >= n) return;
    int nb16 = tile * 16;
    int mrow = lane & 15, q = lane >> 4;
    const float* xp = x + (nb16 + mrow) * 128 + q * 8;
    bf16x8 a[4];
#pragma unroll
    for (int kc = 0; kc < 4; ++kc) {
        float hv[8];
        const float* p = xp + kc * 32;
#pragma unroll
        for (int j = 0; j < 8; ++j) hv[j] = p[j];
        a[kc] = pack8(hv);
    }
    f32x4 acc[4];
#pragma unroll
    for (int t = 0; t < 4; ++t) acc[t] = (f32x4){0.f, 0.f, 0.f, 0.f};
#pragma unroll
    for (int kc = 0; kc < 4; ++kc) {
#pragma unroll
        for (int t = 0; t < 4; ++t) {
            bf16x8 b = *(const bf16x8*)(linT + (t * 16 + mrow) * 128 + kc * 32 + q * 8);
            acc[t] = __builtin_amdgcn_mfma_f32_16x16x32_bf16(a[kc], b, acc[t], 0, 0, 0);
        }
    }
#pragma unroll
    for (int t = 0; t < 4; ++t) {
        int j = t * 16 + mrow;
        float bias = lin_b[j];
#pragma unroll
        for (int r = 0; r < 4; ++r) {
            int node = nb16 + q * 4 + r;
            out[node * 64 + j] = acc[t][r] + bias + h[node * 64 + j];
        }
    }
}

extern "C" void kernel_launch(void* const* d_in, const int* in_sizes, int n_in,
                              void* d_out, int out_size, void* d_ws, size_t ws_size,
                              hipStream_t stream) {
    const float* x = (const float*)d_in[0];
    const float* edge_attr = (const float*)d_in[1];
    const float* mlp_w = (const float*)d_in[2];
    const float* mlp_b = (const float*)d_in[3];
    const float* bn_g = (const float*)d_in[4];
    const float* bn_b = (const float*)d_in[5];
    const float* conv_w = (const float*)d_in[6];
    const float* att_dst = (const float*)d_in[7];
    const float* att_src = (const float*)d_in[8];
    const float* att_edge = (const float*)d_in[9];
    const float* w_ih = (const float*)d_in[10];
    const float* w_hh = (const float*)d_in[11];
    const float* b_ih = (const float*)d_in[12];
    const float* b_hh = (const float*)d_in[13];
    const float* lin_w = (const float*)d_in[14];
    const float* lin_b = (const float*)d_in[15];
    const int* ei = (const int*)d_in[16];

    char* ws = (char*)d_ws;
    float* f_h = (float*)(ws + 0);                // 12,800,000
    ushort_t* mb = (ushort_t*)(ws + 12800000);    // 6,400,000
    ushort_t* xt = (ushort_t*)(ws + 19200000);    // 6,400,000
    uint2* bkt = (uint2*)(ws + 25600000);         // 14,413,824 slack buckets
    uint_t* pk = (uint_t*)(ws + 40013824);        // 6,400,000 dense 4B entries
    float* f_adst = (float*)(ws + 46413824);      // 200,192
    float* f_asrc = (float*)(ws + 46614016);      // 200,192
    int* row_start = (int*)(ws + 46814208);       // 200,448 (n+1)
    float* stats = (float*)(ws + 47014656);       // 32,768 (128 slots, 256B stride)
    int* flag = (int*)(ws + 47047424);            // 512
    ushort_t* wb = (ushort_t*)(ws + 47047936);    // 49,152
    ushort_t* cwb = (ushort_t*)(ws + 47097088);   // 8,192
    ushort_t* mlpT = (ushort_t*)(ws + 47105280);  // 16,384
    ushort_t* linT = (ushort_t*)(ws + 47121664);  // 16,384
    int* gtail = (int*)(ws + 47138048);           // 100,096 (391 slots, 256B stride)

    const size_t needed = 47238144;
    if (ws_size < needed) {
        k_sentinel<<<(out_size + 255) / 256, 256, 0, stream>>>((float*)d_out, out_size);
        return;
    }

    const int n = N_NODES, e = N_EDGES;
    const int gT = ((n + 15) / 16 + 3) / 4;  // 782 (16-node MFMA tiles)
    const int gN4 = (n + 3) / 4;             // 12500
    const int gPrep = 176 + 1 + (NB_BKT + 255) / 256;  // 179
    const float inv_n = 1.0f / (float)n;

    hipMemsetAsync(stats, 0, 32768, stream);

    k_prep<<<gPrep, 256, 0, stream>>>(w_ih, w_hh, conv_w, mlp_w, lin_w, ei, wb, cwb,
                                      mlpT, linT, flag, gtail);
    // bucket-append (782 blocks) || emb MFMA (782 blocks) in one dispatch
    k_embbkt<<<GBK + gT, 256, 0, stream>>>(ei, flag, edge_attr, att_edge, gtail, bkt, e,
                                           x, mlpT, mlp_b, f_h, n);
    // sortb (391 blocks) || BN stats (256 blocks) in one dispatch
    k_statsort<<<NB_BKT + 256, 256, 0, stream>>>(gtail, bkt, pk, row_start, n, f_h,
                                                 stats);
    // step-0 xt with fused BN+ReLU
    k_xt<<<gT, 256, 0, stream>>>(f_h, cwb, att_dst, att_src, bn_g, bn_b, stats, inv_n,
                                 xt, f_adst, f_asrc, n);

    for (int s = 0; s < 3; ++s) {
        k_agg<<<gN4, 256, 0, stream>>>(row_start, pk, f_adst, f_asrc, xt, mb, n);
        k_gruxt<<<gT, 256, 0, stream>>>(mb, f_h, wb, cwb, b_ih, b_hh, att_dst, att_src,
                                        (s < 2) ? 1 : 0, xt, f_adst, f_asrc, n);
    }

    k_out<<<gT, 256, 0, stream>>>(x, linT, lin_b, f_h, (float*)d_out, n);
}